// Round 7
// baseline (531.643 us; speedup 1.0000x reference)
//
#include <hip/hip_runtime.h>

typedef __attribute__((ext_vector_type(8))) short bf16x8;
typedef __attribute__((ext_vector_type(4))) float f32x4;

#define CCH 32   // chunks over L
#define TCH 64   // chunk length

// ---------- bf16 helpers (round-to-nearest-even) ----------
__device__ __forceinline__ unsigned short f2b(float f) {
    unsigned u = __float_as_uint(f);
    return (unsigned short)((u + 0x7fffu + ((u >> 16) & 1u)) >> 16);
}
__device__ __forceinline__ float b2f(unsigned short h) {
    return __uint_as_float(((unsigned)h) << 16);
}
__device__ __forceinline__ float softplus_f(float z) {
    return (z > 15.f) ? z : __logf(1.f + __expf(z));
}
__device__ __forceinline__ float silu_f(float g) {
    return g / (1.f + __expf(-g));
}

// async 16B/lane global->LDS (lds dst = wave-uniform base + lane*16)
__device__ __forceinline__ void gload16(const unsigned short* g, unsigned short* l) {
    __builtin_amdgcn_global_load_lds(
        (const __attribute__((address_space(1))) void*)g,
        (__attribute__((address_space(3))) void*)l, 16, 0, 0);
}

// ---------- fused fp32 -> bf16 cast for all 5 tensors ----------
__global__ __launch_bounds__(256)
void cast_all(const float* __restrict__ h, const float* __restrict__ win,
              const float* __restrict__ wx, const float* __restrict__ wdt,
              const float* __restrict__ wout,
              unsigned short* __restrict__ dh, unsigned short* __restrict__ dwin,
              unsigned short* __restrict__ dwx, unsigned short* __restrict__ dwdt,
              unsigned short* __restrict__ dwout) {
    const int n0 = 1572864, n1 = n0 + 2359296, n2 = n1 + 98304,
              n3 = n2 + 73728, n4 = n3 + 1179648;
    int i = blockIdx.x * 256 + threadIdx.x;
    const float* s; unsigned short* d; int off;
    if (i < n0)      { s = h;    d = dh;    off = i; }
    else if (i < n1) { s = win;  d = dwin;  off = i - n0; }
    else if (i < n2) { s = wx;   d = dwx;   off = i - n1; }
    else if (i < n3) { s = wdt;  d = dwdt;  off = i - n2; }
    else if (i < n4) { s = wout; d = dwout; off = i - n3; }
    else return;
    float4 v = reinterpret_cast<const float4*>(s)[off];
    ushort4 o;
    o.x = f2b(v.x); o.y = f2b(v.y); o.z = f2b(v.z); o.w = f2b(v.w);
    reinterpret_cast<ushort4*>(d)[off] = o;
}

// ---------- MFMA GEMM, 3-stage pipelined async LDS staging ----------
// C[M,N] = A[M,Kc] (bf16, ld lda) x W[N,Kc] (bf16, ld ldw) ^T
// 128x128 tile, BK=32, 4 waves x (64x64 via 4x4 MFMA 16x16x32).
// K-loop: fine-grained s_waitcnt vmcnt(4) + raw s_barrier. At each barrier
// batches k (4 loads/wave) and k+1 are outstanding; vmcnt(4) retires batch k
// (issued 2 compute-phases earlier) while k+1 stays in flight. Each wave
// waits BEFORE the barrier, so after it all waves' batch-k loads are visible.
// OP=0: fp32 store (+ split-K z, C offset kz*czs)
// OP=2: bf16 store, silu applied for col >= silu_col0
// OP=3: bf16 store of softplus(acc + bias[col])
// OP=4: fp32 atomicAdd (split-K accumulate into pre-zeroed C)
template <int OP>
__global__ __launch_bounds__(256)
void gemm_mfma(const unsigned short* __restrict__ A, const unsigned short* __restrict__ W,
               void* __restrict__ Cout, int Kc, int lda, int ldw, int ldc,
               const float* __restrict__ bias, int silu_col0, long long czs) {
    __shared__ unsigned short As[3][4096];   // 3 x 128x32 bf16 = 24 KB
    __shared__ unsigned short Bs[3][4096];
    const int tid = threadIdx.x;
    const int bm = blockIdx.y * 128;
    const int bn = blockIdx.x * 128;
    const int kz = blockIdx.z;
    A += (size_t)kz * Kc;
    W += (size_t)kz * Kc;
    const int lane = tid & 63;
    const int wave = tid >> 6;
    const int r_a = lane >> 2;          // row within 16-row chunk
    const int k8 = (lane & 3) * 8;      // k offset (8 bf16 = 16B)

    const unsigned short* gA0 = A + (size_t)(bm + wave * 16 + r_a) * lda + k8;
    const unsigned short* gA1 = A + (size_t)(bm + 64 + wave * 16 + r_a) * lda + k8;
    const unsigned short* gB0 = W + (size_t)(bn + wave * 16 + r_a) * ldw + k8;
    const unsigned short* gB1 = W + (size_t)(bn + 64 + wave * 16 + r_a) * ldw + k8;

    const int wm = (wave & 1) * 64;
    const int wn = (wave >> 1) * 64;
    const int lr = lane & 15;
    const int quad = lane >> 4;

    f32x4 acc[4][4];
    const f32x4 zero = {0.f, 0.f, 0.f, 0.f};
#pragma unroll
    for (int i = 0; i < 4; i++)
#pragma unroll
        for (int j = 0; j < 4; j++) acc[i][j] = zero;

#define STAGE(koff, j) do { \
        gload16(gA0 + (koff), As[j] + wave * 512); \
        gload16(gA1 + (koff), As[j] + (wave + 4) * 512); \
        gload16(gB0 + (koff), Bs[j] + wave * 512); \
        gload16(gB1 + (koff), Bs[j] + (wave + 4) * 512); \
    } while (0)

    const int niter = Kc >> 5;
    STAGE(0, 0);
    if (niter > 1) STAGE(32, 1);

    int ib = 0;   // LDS buffer holding tile k
    for (int k = 0; k < niter; k++) {
        if (k + 1 < niter)
            asm volatile("s_waitcnt vmcnt(4)\n\ts_barrier" ::: "memory");
        else
            asm volatile("s_waitcnt vmcnt(0)\n\ts_barrier" ::: "memory");
        if (k + 2 < niter) {
            int is_ = ib + 2; if (is_ >= 3) is_ -= 3;
            STAGE((k + 2) << 5, is_);
        }
        const unsigned short* as = As[ib];
        const unsigned short* bs = Bs[ib];
        bf16x8 fa[4], fb[4];
#pragma unroll
        for (int mi = 0; mi < 4; mi++)
            fa[mi] = *reinterpret_cast<const bf16x8*>(as + (wm + mi * 16 + lr) * 32 + quad * 8);
#pragma unroll
        for (int ni = 0; ni < 4; ni++)
            fb[ni] = *reinterpret_cast<const bf16x8*>(bs + (wn + ni * 16 + lr) * 32 + quad * 8);
#pragma unroll
        for (int mi = 0; mi < 4; mi++)
#pragma unroll
            for (int ni = 0; ni < 4; ni++)
                acc[mi][ni] = __builtin_amdgcn_mfma_f32_16x16x32_bf16(fa[mi], fb[ni], acc[mi][ni], 0, 0, 0);
        ib = (ib == 2) ? 0 : ib + 1;
    }
#undef STAGE

    // C/D layout: col = lane&15 (+16*ni), row = quad*4 + reg (+16*mi)
#pragma unroll
    for (int mi = 0; mi < 4; mi++)
#pragma unroll
        for (int reg = 0; reg < 4; reg++) {
            int row = bm + wm + mi * 16 + quad * 4 + reg;
#pragma unroll
            for (int ni = 0; ni < 4; ni++) {
                int col = bn + wn + ni * 16 + lr;
                float v = acc[mi][ni][reg];
                if (OP == 0) {
                    float* Cf = (float*)Cout + (size_t)kz * czs;
                    Cf[(size_t)row * ldc + col] = v;
                } else if (OP == 2) {
                    if (col >= silu_col0) v = silu_f(v);
                    ((unsigned short*)Cout)[(size_t)row * ldc + col] = f2b(v);
                } else if (OP == 3) {
                    ((unsigned short*)Cout)[(size_t)row * ldc + col] = f2b(softplus_f(v + bias[col]));
                } else {  // OP == 4
                    atomicAdd((float*)Cout + (size_t)row * ldc + col, v);
                }
            }
        }
}

// ---------- split-K reduction for x_proj; fuses dtin bf16 extraction ----------
__global__ __launch_bounds__(256)
void reduce_xpart(const float* __restrict__ xpart, float* __restrict__ ssmp,
                  unsigned short* __restrict__ dtin) {
    const int BL = 4096;
    int idx = blockIdx.x * 256 + threadIdx.x;   // BL*32 threads
    int row = idx >> 5;
    int c4 = (idx & 31) * 4;
    float4 s = {0.f, 0.f, 0.f, 0.f};
#pragma unroll
    for (int z = 0; z < 8; z++) {
        float4 v = *reinterpret_cast<const float4*>(xpart + (size_t)z * BL * 128 + (size_t)row * 128 + c4);
        s.x += v.x; s.y += v.y; s.z += v.z; s.w += v.w;
    }
    *reinterpret_cast<float4*>(ssmp + (size_t)row * 128 + c4) = s;
    if (c4 < 96) {
        ushort4 o;
        o.x = f2b(s.x); o.y = f2b(s.y); o.z = f2b(s.z); o.w = f2b(s.w);
        *reinterpret_cast<ushort4*>(dtin + (size_t)row * 96 + c4) = o;
    }
}

// ---------- causal depthwise conv (K=4) + SiLU, 8 channels/thread ----------
__global__ __launch_bounds__(256)
void conv_silu8(const unsigned short* __restrict__ projbf, const float* __restrict__ cw,
                const float* __restrict__ cb, unsigned short* __restrict__ xc) {
    const int I = 3072, L = 2048, LD = 6144;
    int idx = blockIdx.x * 256 + threadIdx.x;    // over BL*I/8
    int i8 = (idx % (I / 8)) * 8;
    int bl = idx / (I / 8);
    int l = bl & (L - 1);
    float s[8];
    {
        float4 b0 = *reinterpret_cast<const float4*>(cb + i8);
        float4 b1 = *reinterpret_cast<const float4*>(cb + i8 + 4);
        s[0]=b0.x; s[1]=b0.y; s[2]=b0.z; s[3]=b0.w; s[4]=b1.x; s[5]=b1.y; s[6]=b1.z; s[7]=b1.w;
    }
    float w[8][4];
#pragma unroll
    for (int c = 0; c < 8; c++) {
        float4 wr = *reinterpret_cast<const float4*>(cw + (i8 + c) * 4);
        w[c][0]=wr.x; w[c][1]=wr.y; w[c][2]=wr.z; w[c][3]=wr.w;
    }
#pragma unroll
    for (int j = 0; j < 4; j++) {
        if (l + j - 3 >= 0) {
            uint4 r = *reinterpret_cast<const uint4*>(projbf + (size_t)(bl + j - 3) * LD + i8);
            float xv[8];
            xv[0]=b2f((unsigned short)(r.x & 0xffff)); xv[1]=b2f((unsigned short)(r.x >> 16));
            xv[2]=b2f((unsigned short)(r.y & 0xffff)); xv[3]=b2f((unsigned short)(r.y >> 16));
            xv[4]=b2f((unsigned short)(r.z & 0xffff)); xv[5]=b2f((unsigned short)(r.z >> 16));
            xv[6]=b2f((unsigned short)(r.w & 0xffff)); xv[7]=b2f((unsigned short)(r.w >> 16));
#pragma unroll
            for (int c = 0; c < 8; c++) s[c] = fmaf(xv[c], w[c][j], s[c]);
        }
    }
    unsigned short o[8];
#pragma unroll
    for (int c = 0; c < 8; c++) o[c] = f2b(silu_f(s[c]));
    uint4 packed;
    packed.x = (unsigned)o[0] | ((unsigned)o[1] << 16);
    packed.y = (unsigned)o[2] | ((unsigned)o[3] << 16);
    packed.z = (unsigned)o[4] | ((unsigned)o[5] << 16);
    packed.w = (unsigned)o[6] | ((unsigned)o[7] << 16);
    *reinterpret_cast<uint4*>(xc + (size_t)bl * I + i8) = packed;
}

// ---------- pass A: per-chunk local scan (init 0) -> S_local, sumDelta ----------
__global__ __launch_bounds__(256)
void scan_passA(const unsigned short* __restrict__ delta_bf, const unsigned short* __restrict__ xc,
                const float* __restrict__ ssmp, const float* __restrict__ Aw,
                float* __restrict__ S_local, float* __restrict__ sumDelta) {
    const int I = 3072, L = 2048;
    __shared__ float bc[TCH][32];
    int g = blockIdx.x * 256 + threadIdx.x;
    int i = g % I;
    int bcid = g / I;
    int c = bcid % CCH;
    int b = bcid / CCH;
    size_t rowbase = (size_t)b * L + (size_t)c * TCH;
    for (int e = threadIdx.x; e < TCH * 8; e += 256) {
        int t = e >> 3, q = e & 7;
        float4 v = *reinterpret_cast<const float4*>(ssmp + (rowbase + t) * 128 + 96 + q * 4);
        *reinterpret_cast<float4*>(&bc[t][q * 4]) = v;
    }
    __syncthreads();

    float Arow[16];
#pragma unroll
    for (int n = 0; n < 16; n++) Arow[n] = Aw[i * 16 + n];
    float st[16];
#pragma unroll
    for (int n = 0; n < 16; n++) st[n] = 0.f;
    float sumD = 0.f;

    size_t rowI = rowbase * I + i;
    for (int t = 0; t < TCH; t++) {
        float delta = b2f(delta_bf[rowI]);
        float du = delta * b2f(xc[rowI]);
        sumD += delta;
        float4 b0 = *reinterpret_cast<const float4*>(&bc[t][0]);
        float4 b1 = *reinterpret_cast<const float4*>(&bc[t][4]);
        float4 b2 = *reinterpret_cast<const float4*>(&bc[t][8]);
        float4 b3 = *reinterpret_cast<const float4*>(&bc[t][12]);
        const float bv[16] = {b0.x,b0.y,b0.z,b0.w, b1.x,b1.y,b1.z,b1.w,
                              b2.x,b2.y,b2.z,b2.w, b3.x,b3.y,b3.z,b3.w};
#pragma unroll
        for (int n = 0; n < 16; n++)
            st[n] = fmaf(st[n], __expf(delta * Arow[n]), du * bv[n]);
        rowI += I;
    }
    size_t obase = (size_t)bcid * 16 * I + i;
#pragma unroll
    for (int n = 0; n < 16; n++) S_local[obase + (size_t)n * I] = st[n];
    sumDelta[(size_t)bcid * I + i] = sumD;
}

// ---------- pass B: sequential combine across chunks -> state_in ----------
__global__ __launch_bounds__(256)
void scan_passB(const float* __restrict__ S_local, const float* __restrict__ sumDelta,
                const float* __restrict__ Aw, float* __restrict__ state_in) {
    const int I = 3072;
    int g = blockIdx.x * 256 + threadIdx.x;
    int i = g % I;
    int bn = g / I;
    int n = bn & 15;
    int b = bn >> 4;
    float a = Aw[i * 16 + n];
    float state = 0.f;
    for (int c = 0; c < CCH; c++) {
        int bcid = b * CCH + c;
        size_t idx = ((size_t)bcid * 16 + n) * I + i;
        state_in[idx] = state;
        state = fmaf(state, __expf(a * sumDelta[(size_t)bcid * I + i]), S_local[idx]);
    }
}

// ---------- pass C: re-scan from state_in; fused y, D-skip, pre-silu'd gate ----------
__global__ __launch_bounds__(256)
void scan_passC(const unsigned short* __restrict__ projbf,   // silu(gate) at col 3072+i, ld 6144
                const unsigned short* __restrict__ xc,
                const float* __restrict__ ssmp, const unsigned short* __restrict__ delta_bf,
                const float* __restrict__ Aw, const float* __restrict__ Dw,
                const float* __restrict__ state_in, unsigned short* __restrict__ ybf) {
    const int I = 3072, L = 2048, LD = 6144;
    __shared__ float bc[TCH][32];
    int g = blockIdx.x * 256 + threadIdx.x;
    int i = g % I;
    int bcid = g / I;
    int c = bcid % CCH;
    int b = bcid / CCH;
    size_t rowbase = (size_t)b * L + (size_t)c * TCH;
    for (int e = threadIdx.x; e < TCH * 8; e += 256) {
        int t = e >> 3, q = e & 7;
        float4 v = *reinterpret_cast<const float4*>(ssmp + (rowbase + t) * 128 + 96 + q * 4);
        *reinterpret_cast<float4*>(&bc[t][q * 4]) = v;
    }
    __syncthreads();

    float Arow[16];
#pragma unroll
    for (int n = 0; n < 16; n++) Arow[n] = Aw[i * 16 + n];
    float Dv = Dw[i];
    float st[16];
    size_t sbase = (size_t)bcid * 16 * I + i;
#pragma unroll
    for (int n = 0; n < 16; n++) st[n] = state_in[sbase + (size_t)n * I];

    size_t rowI = rowbase * I + i;
    size_t rowG = rowbase * LD + I + i;
    for (int t = 0; t < TCH; t++) {
        float delta = b2f(delta_bf[rowI]);
        float u = b2f(xc[rowI]);
        float du = delta * u;
        float4 b0 = *reinterpret_cast<const float4*>(&bc[t][0]);
        float4 b1 = *reinterpret_cast<const float4*>(&bc[t][4]);
        float4 b2 = *reinterpret_cast<const float4*>(&bc[t][8]);
        float4 b3 = *reinterpret_cast<const float4*>(&bc[t][12]);
        float4 c0 = *reinterpret_cast<const float4*>(&bc[t][16]);
        float4 c1 = *reinterpret_cast<const float4*>(&bc[t][20]);
        float4 c2 = *reinterpret_cast<const float4*>(&bc[t][24]);
        float4 c3 = *reinterpret_cast<const float4*>(&bc[t][28]);
        const float bv[16] = {b0.x,b0.y,b0.z,b0.w, b1.x,b1.y,b1.z,b1.w,
                              b2.x,b2.y,b2.z,b2.w, b3.x,b3.y,b3.z,b3.w};
        const float cv[16] = {c0.x,c0.y,c0.z,c0.w, c1.x,c1.y,c1.z,c1.w,
                              c2.x,c2.y,c2.z,c2.w, c3.x,c3.y,c3.z,c3.w};
        float y = 0.f;
#pragma unroll
        for (int n = 0; n < 16; n++) {
            st[n] = fmaf(st[n], __expf(delta * Arow[n]), du * bv[n]);
            y = fmaf(st[n], cv[n], y);
        }
        y = fmaf(u, Dv, y);
        y *= b2f(projbf[rowG]);            // gate already silu'd in GEMM epilogue
        ybf[rowI] = f2b(y);
        rowI += I;
        rowG += LD;
    }
}

extern "C" void kernel_launch(void* const* d_in, const int* in_sizes, int n_in,
                              void* d_out, int out_size, void* d_ws, size_t ws_size,
                              hipStream_t stream) {
    const float* hidden  = (const float*)d_in[0];
    const float* W_in    = (const float*)d_in[1];
    const float* conv_w  = (const float*)d_in[2];
    const float* conv_b  = (const float*)d_in[3];
    const float* W_x     = (const float*)d_in[4];
    const float* W_dt    = (const float*)d_in[5];
    const float* dt_bias = (const float*)d_in[6];
    const float* Aw      = (const float*)d_in[7];
    const float* Dw      = (const float*)d_in[8];
    const float* W_out   = (const float*)d_in[9];
    float* out = (float*)d_out;

    constexpr int Bsz = 2, L = 2048, H = 1536, I = 3072, R = 96;
    constexpr int BL = Bsz * L;        // 4096
    constexpr int TwoI = 2 * I;        // 6144

    // ---- workspace layout ----
    char* base = (char*)d_ws;
    unsigned short* proj_bf  = (unsigned short*)base; base += (size_t)BL * TwoI * 2;   // 50.3 MB
    unsigned short* delta_bf = (unsigned short*)base; base += (size_t)BL * I * 2;      // 25.2 MB
    unsigned short* xc_bf    = (unsigned short*)base; base += (size_t)BL * I * 2;      // 25.2 MB
    unsigned short* y_bf     = (unsigned short*)base; base += (size_t)BL * I * 2;      // 25.2 MB
    float* ssmp              = (float*)base;          base += (size_t)BL * 128 * 4;    // 2.1 MB
    float* xpart             = (float*)base;          base += (size_t)8 * BL * 128 * 4;// 16.8 MB
    unsigned short* dtin_bf  = (unsigned short*)base; base += (size_t)BL * R * 2;      // 0.8 MB
    unsigned short* wx_bf    = (unsigned short*)base; base += (size_t)128 * I * 2;     // 0.8 MB
    unsigned short* wdt_bf   = (unsigned short*)base; base += (size_t)I * R * 2;       // 0.6 MB
    unsigned short* wout_bf  = (unsigned short*)base; base += (size_t)H * I * 2;       // 9.4 MB
    unsigned short* h_bf     = (unsigned short*)base; base += (size_t)BL * H * 2;      // 12.6 MB
    unsigned short* win_bf   = (unsigned short*)base; base += (size_t)TwoI * H * 2;    // 18.9 MB
    // scan scratch overlays h_bf+win_bf (dead after in_proj): 26.0 <= 31.5 MB
    float* S_local  = (float*)h_bf;
    float* sumDelta = S_local + (size_t)Bsz * CCH * 16 * I;
    float* state_in = sumDelta + (size_t)Bsz * CCH * I;

    dim3 blk(256);

    // 0) zero d_out for atomic split-K accumulate; fused weight/act casts
    hipMemsetAsync(out, 0, (size_t)BL * H * 4, stream);
    cast_all<<<(5283840 + 255) / 256, blk, 0, stream>>>(
        hidden, W_in, W_x, W_dt, W_out, h_bf, win_bf, wx_bf, wdt_bf, wout_bf);

    // 1) in_proj -> proj_bf [4096,6144] bf16; silu on gate half (cols >= 3072)
    gemm_mfma<2><<<dim3(TwoI / 128, BL / 128, 1), blk, 0, stream>>>(
        h_bf, win_bf, proj_bf, H, H, H, TwoI, nullptr, I, 0);

    // 2) causal conv + SiLU -> xc_bf
    conv_silu8<<<BL * I / 8 / 256, blk, 0, stream>>>(proj_bf, conv_w, conv_b, xc_bf);

    // 3) x_proj split-K x8: xpart[z][4096][128] = xc @ wx^T (K chunk 384)
    gemm_mfma<0><<<dim3(1, BL / 128, 8), blk, 0, stream>>>(
        xc_bf, wx_bf, xpart, I / 8, I, I, 128, nullptr, 0, (long long)BL * 128);
    reduce_xpart<<<BL * 32 / 256, blk, 0, stream>>>(xpart, ssmp, dtin_bf);

    // 4) dt_proj, fused +bias & softplus -> delta_bf [4096,3072] bf16
    gemm_mfma<3><<<dim3(I / 128, BL / 128, 1), blk, 0, stream>>>(
        dtin_bf, wdt_bf, delta_bf, R, R, R, I, dt_bias, 0, 0);

    // 5) chunk-parallel selective scan
    scan_passA<<<Bsz * I * CCH / 256, blk, 0, stream>>>(
        delta_bf, xc_bf, ssmp, Aw, S_local, sumDelta);
    scan_passB<<<Bsz * 16 * I / 256, blk, 0, stream>>>(
        S_local, sumDelta, Aw, state_in);
    scan_passC<<<Bsz * I * CCH / 256, blk, 0, stream>>>(
        proj_bf, xc_bf, ssmp, delta_bf, Aw, Dw, state_in, y_bf);

    // 6) out_proj split-K x4, atomic fp32 accumulate -> out [4096,1536]
    gemm_mfma<4><<<dim3(H / 128, BL / 128, 4), blk, 0, stream>>>(
        y_bf, wout_bf, out, I / 4, I, I, H, nullptr, 0, 0);
}

// Round 8
// 479.582 us; speedup vs baseline: 1.1086x; 1.1086x over previous
//
#include <hip/hip_runtime.h>

typedef __attribute__((ext_vector_type(8))) short bf16x8;
typedef __attribute__((ext_vector_type(4))) float f32x4;

#define CCH 32   // chunks over L
#define TCH 64   // chunk length

// ---------- bf16 helpers (round-to-nearest-even) ----------
__device__ __forceinline__ unsigned short f2b(float f) {
    unsigned u = __float_as_uint(f);
    return (unsigned short)((u + 0x7fffu + ((u >> 16) & 1u)) >> 16);
}
__device__ __forceinline__ float b2f(unsigned short h) {
    return __uint_as_float(((unsigned)h) << 16);
}
__device__ __forceinline__ float softplus_f(float z) {
    return (z > 15.f) ? z : __logf(1.f + __expf(z));
}
__device__ __forceinline__ float silu_f(float g) {
    return g / (1.f + __expf(-g));
}

// async 16B/lane global->LDS (lds dst = wave-uniform base + lane*16)
__device__ __forceinline__ void gload16(const unsigned short* g, unsigned short* l) {
    __builtin_amdgcn_global_load_lds(
        (const __attribute__((address_space(1))) void*)g,
        (__attribute__((address_space(3))) void*)l, 16, 0, 0);
}

// ---------- fused fp32 -> bf16 cast for all 5 tensors ----------
__global__ __launch_bounds__(256)
void cast_all(const float* __restrict__ h, const float* __restrict__ win,
              const float* __restrict__ wx, const float* __restrict__ wdt,
              const float* __restrict__ wout,
              unsigned short* __restrict__ dh, unsigned short* __restrict__ dwin,
              unsigned short* __restrict__ dwx, unsigned short* __restrict__ dwdt,
              unsigned short* __restrict__ dwout) {
    const int n0 = 1572864, n1 = n0 + 2359296, n2 = n1 + 98304,
              n3 = n2 + 73728, n4 = n3 + 1179648;
    int i = blockIdx.x * 256 + threadIdx.x;
    const float* s; unsigned short* d; int off;
    if (i < n0)      { s = h;    d = dh;    off = i; }
    else if (i < n1) { s = win;  d = dwin;  off = i - n0; }
    else if (i < n2) { s = wx;   d = dwx;   off = i - n1; }
    else if (i < n3) { s = wdt;  d = dwdt;  off = i - n2; }
    else if (i < n4) { s = wout; d = dwout; off = i - n3; }
    else return;
    float4 v = reinterpret_cast<const float4*>(s)[off];
    ushort4 o;
    o.x = f2b(v.x); o.y = f2b(v.y); o.z = f2b(v.z); o.w = f2b(v.w);
    reinterpret_cast<ushort4*>(d)[off] = o;
}

// ---------- MFMA GEMM, 3-stage pipelined async LDS staging ----------
// C[M,N] = A[M,Kc] (bf16, ld lda) x W[N,Kc] (bf16, ld ldw) ^T
// 128x128 tile, BK=32, 4 waves x (64x64 via 4x4 MFMA 16x16x32).
// K-loop: fine-grained s_waitcnt vmcnt(4) + raw s_barrier. At each barrier
// batches k (4 loads/wave) and k+1 are outstanding; vmcnt(4) retires batch k
// (issued 2 compute-phases earlier) while k+1 stays in flight.
// OP=0: fp32 store (+ split-K z, C offset kz*czs)
// OP=2: bf16 store, silu applied for col >= silu_col0
// OP=3: bf16 store of softplus(acc + bias[col])
template <int OP>
__global__ __launch_bounds__(256)
void gemm_mfma(const unsigned short* __restrict__ A, const unsigned short* __restrict__ W,
               void* __restrict__ Cout, int Kc, int lda, int ldw, int ldc,
               const float* __restrict__ bias, int silu_col0, long long czs) {
    __shared__ unsigned short As[3][4096];   // 3 x 128x32 bf16 = 24 KB
    __shared__ unsigned short Bs[3][4096];
    const int tid = threadIdx.x;
    const int bm = blockIdx.y * 128;
    const int bn = blockIdx.x * 128;
    const int kz = blockIdx.z;
    A += (size_t)kz * Kc;
    W += (size_t)kz * Kc;
    const int lane = tid & 63;
    const int wave = tid >> 6;
    const int r_a = lane >> 2;          // row within 16-row chunk
    const int k8 = (lane & 3) * 8;      // k offset (8 bf16 = 16B)

    const unsigned short* gA0 = A + (size_t)(bm + wave * 16 + r_a) * lda + k8;
    const unsigned short* gA1 = A + (size_t)(bm + 64 + wave * 16 + r_a) * lda + k8;
    const unsigned short* gB0 = W + (size_t)(bn + wave * 16 + r_a) * ldw + k8;
    const unsigned short* gB1 = W + (size_t)(bn + 64 + wave * 16 + r_a) * ldw + k8;

    const int wm = (wave & 1) * 64;
    const int wn = (wave >> 1) * 64;
    const int lr = lane & 15;
    const int quad = lane >> 4;

    f32x4 acc[4][4];
    const f32x4 zero = {0.f, 0.f, 0.f, 0.f};
#pragma unroll
    for (int i = 0; i < 4; i++)
#pragma unroll
        for (int j = 0; j < 4; j++) acc[i][j] = zero;

#define STAGE(koff, j) do { \
        gload16(gA0 + (koff), As[j] + wave * 512); \
        gload16(gA1 + (koff), As[j] + (wave + 4) * 512); \
        gload16(gB0 + (koff), Bs[j] + wave * 512); \
        gload16(gB1 + (koff), Bs[j] + (wave + 4) * 512); \
    } while (0)

    const int niter = Kc >> 5;
    STAGE(0, 0);
    if (niter > 1) STAGE(32, 1);

    int ib = 0;   // LDS buffer holding tile k
    for (int k = 0; k < niter; k++) {
        if (k + 1 < niter)
            asm volatile("s_waitcnt vmcnt(4)\n\ts_barrier" ::: "memory");
        else
            asm volatile("s_waitcnt vmcnt(0)\n\ts_barrier" ::: "memory");
        if (k + 2 < niter) {
            int is_ = ib + 2; if (is_ >= 3) is_ -= 3;
            STAGE((k + 2) << 5, is_);
        }
        const unsigned short* as = As[ib];
        const unsigned short* bs = Bs[ib];
        bf16x8 fa[4], fb[4];
#pragma unroll
        for (int mi = 0; mi < 4; mi++)
            fa[mi] = *reinterpret_cast<const bf16x8*>(as + (wm + mi * 16 + lr) * 32 + quad * 8);
#pragma unroll
        for (int ni = 0; ni < 4; ni++)
            fb[ni] = *reinterpret_cast<const bf16x8*>(bs + (wn + ni * 16 + lr) * 32 + quad * 8);
#pragma unroll
        for (int mi = 0; mi < 4; mi++)
#pragma unroll
            for (int ni = 0; ni < 4; ni++)
                acc[mi][ni] = __builtin_amdgcn_mfma_f32_16x16x32_bf16(fa[mi], fb[ni], acc[mi][ni], 0, 0, 0);
        ib = (ib == 2) ? 0 : ib + 1;
    }
#undef STAGE

    // C/D layout: col = lane&15 (+16*ni), row = quad*4 + reg (+16*mi)
#pragma unroll
    for (int mi = 0; mi < 4; mi++)
#pragma unroll
        for (int reg = 0; reg < 4; reg++) {
            int row = bm + wm + mi * 16 + quad * 4 + reg;
#pragma unroll
            for (int ni = 0; ni < 4; ni++) {
                int col = bn + wn + ni * 16 + lr;
                float v = acc[mi][ni][reg];
                if (OP == 0) {
                    float* Cf = (float*)Cout + (size_t)kz * czs;
                    Cf[(size_t)row * ldc + col] = v;
                } else if (OP == 2) {
                    if (col >= silu_col0) v = silu_f(v);
                    ((unsigned short*)Cout)[(size_t)row * ldc + col] = f2b(v);
                } else {  // OP == 3
                    ((unsigned short*)Cout)[(size_t)row * ldc + col] = f2b(softplus_f(v + bias[col]));
                }
            }
        }
}

// ---------- sum of 2 split-K partials -> out (float4) ----------
__global__ __launch_bounds__(256)
void reduce_out(const float* __restrict__ p, float* __restrict__ out, int n4) {
    int i = blockIdx.x * 256 + threadIdx.x;
    if (i >= n4) return;
    float4 a = reinterpret_cast<const float4*>(p)[i];
    float4 b = reinterpret_cast<const float4*>(p + (size_t)n4 * 4)[i];
    float4 o = {a.x + b.x, a.y + b.y, a.z + b.z, a.w + b.w};
    reinterpret_cast<float4*>(out)[i] = o;
}

// ---------- split-K reduction for x_proj; fuses dtin bf16 extraction ----------
__global__ __launch_bounds__(256)
void reduce_xpart(const float* __restrict__ xpart, float* __restrict__ ssmp,
                  unsigned short* __restrict__ dtin) {
    const int BL = 4096;
    int idx = blockIdx.x * 256 + threadIdx.x;   // BL*32 threads
    int row = idx >> 5;
    int c4 = (idx & 31) * 4;
    float4 s = {0.f, 0.f, 0.f, 0.f};
#pragma unroll
    for (int z = 0; z < 8; z++) {
        float4 v = *reinterpret_cast<const float4*>(xpart + (size_t)z * BL * 128 + (size_t)row * 128 + c4);
        s.x += v.x; s.y += v.y; s.z += v.z; s.w += v.w;
    }
    *reinterpret_cast<float4*>(ssmp + (size_t)row * 128 + c4) = s;
    if (c4 < 96) {
        ushort4 o;
        o.x = f2b(s.x); o.y = f2b(s.y); o.z = f2b(s.z); o.w = f2b(s.w);
        *reinterpret_cast<ushort4*>(dtin + (size_t)row * 96 + c4) = o;
    }
}

// ---------- causal depthwise conv (K=4) + SiLU, 8 channels/thread ----------
__global__ __launch_bounds__(256)
void conv_silu8(const unsigned short* __restrict__ projbf, const float* __restrict__ cw,
                const float* __restrict__ cb, unsigned short* __restrict__ xc) {
    const int I = 3072, L = 2048, LD = 6144;
    int idx = blockIdx.x * 256 + threadIdx.x;    // over BL*I/8
    int i8 = (idx % (I / 8)) * 8;
    int bl = idx / (I / 8);
    int l = bl & (L - 1);
    float s[8];
    {
        float4 b0 = *reinterpret_cast<const float4*>(cb + i8);
        float4 b1 = *reinterpret_cast<const float4*>(cb + i8 + 4);
        s[0]=b0.x; s[1]=b0.y; s[2]=b0.z; s[3]=b0.w; s[4]=b1.x; s[5]=b1.y; s[6]=b1.z; s[7]=b1.w;
    }
    float w[8][4];
#pragma unroll
    for (int c = 0; c < 8; c++) {
        float4 wr = *reinterpret_cast<const float4*>(cw + (i8 + c) * 4);
        w[c][0]=wr.x; w[c][1]=wr.y; w[c][2]=wr.z; w[c][3]=wr.w;
    }
#pragma unroll
    for (int j = 0; j < 4; j++) {
        if (l + j - 3 >= 0) {
            uint4 r = *reinterpret_cast<const uint4*>(projbf + (size_t)(bl + j - 3) * LD + i8);
            float xv[8];
            xv[0]=b2f((unsigned short)(r.x & 0xffff)); xv[1]=b2f((unsigned short)(r.x >> 16));
            xv[2]=b2f((unsigned short)(r.y & 0xffff)); xv[3]=b2f((unsigned short)(r.y >> 16));
            xv[4]=b2f((unsigned short)(r.z & 0xffff)); xv[5]=b2f((unsigned short)(r.z >> 16));
            xv[6]=b2f((unsigned short)(r.w & 0xffff)); xv[7]=b2f((unsigned short)(r.w >> 16));
#pragma unroll
            for (int c = 0; c < 8; c++) s[c] = fmaf(xv[c], w[c][j], s[c]);
        }
    }
    unsigned short o[8];
#pragma unroll
    for (int c = 0; c < 8; c++) o[c] = f2b(silu_f(s[c]));
    uint4 packed;
    packed.x = (unsigned)o[0] | ((unsigned)o[1] << 16);
    packed.y = (unsigned)o[2] | ((unsigned)o[3] << 16);
    packed.z = (unsigned)o[4] | ((unsigned)o[5] << 16);
    packed.w = (unsigned)o[6] | ((unsigned)o[7] << 16);
    *reinterpret_cast<uint4*>(xc + (size_t)bl * I + i8) = packed;
}

// ---------- pass A: per-chunk local scan (init 0) -> S_local, sumDelta ----------
__global__ __launch_bounds__(256)
void scan_passA(const unsigned short* __restrict__ delta_bf, const unsigned short* __restrict__ xc,
                const float* __restrict__ ssmp, const float* __restrict__ Aw,
                float* __restrict__ S_local, float* __restrict__ sumDelta) {
    const int I = 3072, L = 2048;
    __shared__ float bc[TCH][32];
    int g = blockIdx.x * 256 + threadIdx.x;
    int i = g % I;
    int bcid = g / I;
    int c = bcid % CCH;
    int b = bcid / CCH;
    size_t rowbase = (size_t)b * L + (size_t)c * TCH;
    for (int e = threadIdx.x; e < TCH * 8; e += 256) {
        int t = e >> 3, q = e & 7;
        float4 v = *reinterpret_cast<const float4*>(ssmp + (rowbase + t) * 128 + 96 + q * 4);
        *reinterpret_cast<float4*>(&bc[t][q * 4]) = v;
    }
    __syncthreads();

    float Arow[16];
#pragma unroll
    for (int n = 0; n < 16; n++) Arow[n] = Aw[i * 16 + n];
    float st[16];
#pragma unroll
    for (int n = 0; n < 16; n++) st[n] = 0.f;
    float sumD = 0.f;

    size_t rowI = rowbase * I + i;
    for (int t = 0; t < TCH; t++) {
        float delta = b2f(delta_bf[rowI]);
        float du = delta * b2f(xc[rowI]);
        sumD += delta;
        float4 b0 = *reinterpret_cast<const float4*>(&bc[t][0]);
        float4 b1 = *reinterpret_cast<const float4*>(&bc[t][4]);
        float4 b2 = *reinterpret_cast<const float4*>(&bc[t][8]);
        float4 b3 = *reinterpret_cast<const float4*>(&bc[t][12]);
        const float bv[16] = {b0.x,b0.y,b0.z,b0.w, b1.x,b1.y,b1.z,b1.w,
                              b2.x,b2.y,b2.z,b2.w, b3.x,b3.y,b3.z,b3.w};
#pragma unroll
        for (int n = 0; n < 16; n++)
            st[n] = fmaf(st[n], __expf(delta * Arow[n]), du * bv[n]);
        rowI += I;
    }
    size_t obase = (size_t)bcid * 16 * I + i;
#pragma unroll
    for (int n = 0; n < 16; n++) S_local[obase + (size_t)n * I] = st[n];
    sumDelta[(size_t)bcid * I + i] = sumD;
}

// ---------- pass B: sequential combine across chunks -> state_in ----------
__global__ __launch_bounds__(256)
void scan_passB(const float* __restrict__ S_local, const float* __restrict__ sumDelta,
                const float* __restrict__ Aw, float* __restrict__ state_in) {
    const int I = 3072;
    int g = blockIdx.x * 256 + threadIdx.x;
    int i = g % I;
    int bn = g / I;
    int n = bn & 15;
    int b = bn >> 4;
    float a = Aw[i * 16 + n];
    float state = 0.f;
    for (int c = 0; c < CCH; c++) {
        int bcid = b * CCH + c;
        size_t idx = ((size_t)bcid * 16 + n) * I + i;
        state_in[idx] = state;
        state = fmaf(state, __expf(a * sumDelta[(size_t)bcid * I + i]), S_local[idx]);
    }
}

// ---------- pass C: re-scan from state_in; fused y, D-skip, pre-silu'd gate ----------
__global__ __launch_bounds__(256)
void scan_passC(const unsigned short* __restrict__ projbf,   // silu(gate) at col 3072+i, ld 6144
                const unsigned short* __restrict__ xc,
                const float* __restrict__ ssmp, const unsigned short* __restrict__ delta_bf,
                const float* __restrict__ Aw, const float* __restrict__ Dw,
                const float* __restrict__ state_in, unsigned short* __restrict__ ybf) {
    const int I = 3072, L = 2048, LD = 6144;
    __shared__ float bc[TCH][32];
    int g = blockIdx.x * 256 + threadIdx.x;
    int i = g % I;
    int bcid = g / I;
    int c = bcid % CCH;
    int b = bcid / CCH;
    size_t rowbase = (size_t)b * L + (size_t)c * TCH;
    for (int e = threadIdx.x; e < TCH * 8; e += 256) {
        int t = e >> 3, q = e & 7;
        float4 v = *reinterpret_cast<const float4*>(ssmp + (rowbase + t) * 128 + 96 + q * 4);
        *reinterpret_cast<float4*>(&bc[t][q * 4]) = v;
    }
    __syncthreads();

    float Arow[16];
#pragma unroll
    for (int n = 0; n < 16; n++) Arow[n] = Aw[i * 16 + n];
    float Dv = Dw[i];
    float st[16];
    size_t sbase = (size_t)bcid * 16 * I + i;
#pragma unroll
    for (int n = 0; n < 16; n++) st[n] = state_in[sbase + (size_t)n * I];

    size_t rowI = rowbase * I + i;
    size_t rowG = rowbase * LD + I + i;
    for (int t = 0; t < TCH; t++) {
        float delta = b2f(delta_bf[rowI]);
        float u = b2f(xc[rowI]);
        float du = delta * u;
        float4 b0 = *reinterpret_cast<const float4*>(&bc[t][0]);
        float4 b1 = *reinterpret_cast<const float4*>(&bc[t][4]);
        float4 b2 = *reinterpret_cast<const float4*>(&bc[t][8]);
        float4 b3 = *reinterpret_cast<const float4*>(&bc[t][12]);
        float4 c0 = *reinterpret_cast<const float4*>(&bc[t][16]);
        float4 c1 = *reinterpret_cast<const float4*>(&bc[t][20]);
        float4 c2 = *reinterpret_cast<const float4*>(&bc[t][24]);
        float4 c3 = *reinterpret_cast<const float4*>(&bc[t][28]);
        const float bv[16] = {b0.x,b0.y,b0.z,b0.w, b1.x,b1.y,b1.z,b1.w,
                              b2.x,b2.y,b2.z,b2.w, b3.x,b3.y,b3.z,b3.w};
        const float cv[16] = {c0.x,c0.y,c0.z,c0.w, c1.x,c1.y,c1.z,c1.w,
                              c2.x,c2.y,c2.z,c2.w, c3.x,c3.y,c3.z,c3.w};
        float y = 0.f;
#pragma unroll
        for (int n = 0; n < 16; n++) {
            st[n] = fmaf(st[n], __expf(delta * Arow[n]), du * bv[n]);
            y = fmaf(st[n], cv[n], y);
        }
        y = fmaf(u, Dv, y);
        y *= b2f(projbf[rowG]);            // gate already silu'd in GEMM epilogue
        ybf[rowI] = f2b(y);
        rowI += I;
        rowG += LD;
    }
}

extern "C" void kernel_launch(void* const* d_in, const int* in_sizes, int n_in,
                              void* d_out, int out_size, void* d_ws, size_t ws_size,
                              hipStream_t stream) {
    const float* hidden  = (const float*)d_in[0];
    const float* W_in    = (const float*)d_in[1];
    const float* conv_w  = (const float*)d_in[2];
    const float* conv_b  = (const float*)d_in[3];
    const float* W_x     = (const float*)d_in[4];
    const float* W_dt    = (const float*)d_in[5];
    const float* dt_bias = (const float*)d_in[6];
    const float* Aw      = (const float*)d_in[7];
    const float* Dw      = (const float*)d_in[8];
    const float* W_out   = (const float*)d_in[9];
    float* out = (float*)d_out;

    constexpr int Bsz = 2, L = 2048, H = 1536, I = 3072, R = 96;
    constexpr int BL = Bsz * L;        // 4096
    constexpr int TwoI = 2 * I;        // 6144

    // ---- workspace layout ----
    char* base = (char*)d_ws;
    unsigned short* proj_bf  = (unsigned short*)base; base += (size_t)BL * TwoI * 2;   // 50.3 MB
    unsigned short* delta_bf = (unsigned short*)base; base += (size_t)BL * I * 2;      // 25.2 MB
    unsigned short* xc_bf    = (unsigned short*)base; base += (size_t)BL * I * 2;      // 25.2 MB
    unsigned short* y_bf     = (unsigned short*)base; base += (size_t)BL * I * 2;      // 25.2 MB
    float* ssmp              = (float*)base;          base += (size_t)BL * 128 * 4;    // 2.1 MB
    float* xpart             = (float*)base;          base += (size_t)8 * BL * 128 * 4;// 16.8 MB
    unsigned short* dtin_bf  = (unsigned short*)base; base += (size_t)BL * R * 2;      // 0.8 MB
    unsigned short* wx_bf    = (unsigned short*)base; base += (size_t)128 * I * 2;     // 0.8 MB
    unsigned short* wdt_bf   = (unsigned short*)base; base += (size_t)I * R * 2;       // 0.6 MB
    unsigned short* wout_bf  = (unsigned short*)base; base += (size_t)H * I * 2;       // 9.4 MB
    unsigned short* h_bf     = (unsigned short*)base; base += (size_t)BL * H * 2;      // 12.6 MB
    unsigned short* win_bf   = (unsigned short*)base; base += (size_t)TwoI * H * 2;    // 18.9 MB
    // scan scratch overlays h_bf+win_bf (dead after in_proj): 26.0 <= 31.5 MB
    float* S_local  = (float*)h_bf;
    float* sumDelta = S_local + (size_t)Bsz * CCH * 16 * I;
    float* state_in = sumDelta + (size_t)Bsz * CCH * I;
    // out_proj split-K partials overlay proj_bf (dead after passC):
    // 2 * 4096*1536*4 B = 50.3 MB == proj_bf size
    float* opart = (float*)proj_bf;

    dim3 blk(256);

    // 0) fused weight/act casts
    cast_all<<<(5283840 + 255) / 256, blk, 0, stream>>>(
        hidden, W_in, W_x, W_dt, W_out, h_bf, win_bf, wx_bf, wdt_bf, wout_bf);

    // 1) in_proj -> proj_bf [4096,6144] bf16; silu on gate half (cols >= 3072)
    gemm_mfma<2><<<dim3(TwoI / 128, BL / 128, 1), blk, 0, stream>>>(
        h_bf, win_bf, proj_bf, H, H, H, TwoI, nullptr, I, 0);

    // 2) causal conv + SiLU -> xc_bf
    conv_silu8<<<BL * I / 8 / 256, blk, 0, stream>>>(proj_bf, conv_w, conv_b, xc_bf);

    // 3) x_proj split-K x8: xpart[z][4096][128] = xc @ wx^T (K chunk 384)
    gemm_mfma<0><<<dim3(1, BL / 128, 8), blk, 0, stream>>>(
        xc_bf, wx_bf, xpart, I / 8, I, I, 128, nullptr, 0, (long long)BL * 128);
    reduce_xpart<<<BL * 32 / 256, blk, 0, stream>>>(xpart, ssmp, dtin_bf);

    // 4) dt_proj, fused +bias & softplus -> delta_bf [4096,3072] bf16
    gemm_mfma<3><<<dim3(I / 128, BL / 128, 1), blk, 0, stream>>>(
        dtin_bf, wdt_bf, delta_bf, R, R, R, I, dt_bias, 0, 0);

    // 5) chunk-parallel selective scan
    scan_passA<<<Bsz * I * CCH / 256, blk, 0, stream>>>(
        delta_bf, xc_bf, ssmp, Aw, S_local, sumDelta);
    scan_passB<<<Bsz * 16 * I / 256, blk, 0, stream>>>(
        S_local, sumDelta, Aw, state_in);
    scan_passC<<<Bsz * I * CCH / 256, blk, 0, stream>>>(
        proj_bf, xc_bf, ssmp, delta_bf, Aw, Dw, state_in, y_bf);

    // 6) out_proj split-K x2, deterministic fp32 partials -> opart; then sum
    gemm_mfma<0><<<dim3(H / 128, BL / 128, 2), blk, 0, stream>>>(
        y_bf, wout_bf, opart, I / 2, I, I, H, nullptr, 0, (long long)BL * H);
    reduce_out<<<BL * H / 4 / 256, blk, 0, stream>>>(opart, out, BL * H / 4);
}